// Round 5
// baseline (761.644 us; speedup 1.0000x reference)
//
#include <hip/hip_runtime.h>

// Problem constants
#define B_ 2
#define L_ 2048
#define D_ 2048
#define NH_ 16
#define KH_ 8
#define HD_ 128

typedef __attribute__((ext_vector_type(8))) short short8;
typedef __attribute__((ext_vector_type(4))) float floatx4;

__device__ __forceinline__ unsigned short f2bf(float f) {
  unsigned u = __float_as_uint(f);
  unsigned r = (u + 0x7fffu + ((u >> 16) & 1u)) >> 16;
  return (unsigned short)r;
}
__device__ __forceinline__ float bf2f(unsigned short h) {
  return __uint_as_float(((unsigned)h) << 16);
}
__device__ __forceinline__ void gl_lds16(const void* g, void* l) {
  __builtin_amdgcn_global_load_lds(
      (const __attribute__((address_space(1))) unsigned int*)g,
      (__attribute__((address_space(3))) unsigned int*)l, 16, 0, 0);
}

// ---------------- convert x: fp32 -> bf16 ----------------
__global__ __launch_bounds__(256) void cvt_f32_bf16(const float* __restrict__ in,
                                                    unsigned short* __restrict__ out) {
  long i = ((long)blockIdx.x * 256 + threadIdx.x) * 4;
  float4 v = *(const float4*)(in + i);
  ushort4 o;
  o.x = f2bf(v.x); o.y = f2bf(v.y); o.z = f2bf(v.z); o.w = f2bf(v.w);
  *(ushort4*)(out + i) = o;
}

// ----- fused transpose+convert of all weights: one launch, task decoded from blockIdx -----
// out[c][r] = in[r][c]; all outputs have row stride 2048 (the K dim of the GEMMs).
__global__ __launch_bounds__(256) void transpose_all(const float* __restrict__ wq,
                                                     const float* __restrict__ wk,
                                                     const float* __restrict__ wv,
                                                     const float* __restrict__ wo,
                                                     unsigned short* __restrict__ wqkv_t,
                                                     unsigned short* __restrict__ wo_t) {
  __shared__ float tile[32][33];
  int id = blockIdx.x;
  const float* in;
  unsigned short* out;
  int C, sh;
  if (id < 4096) {
    in = wq; out = wqkv_t; C = 2048; sh = 6;
  } else if (id < 6144) {
    in = wk; out = wqkv_t + 2048L * 2048; C = 1024; sh = 5; id -= 4096;
  } else if (id < 8192) {
    in = wv; out = wqkv_t + 3072L * 2048; C = 1024; sh = 5; id -= 6144;
  } else {
    in = wo; out = wo_t; C = 2048; sh = 6; id -= 8192;
  }
  int c0 = (id & ((1 << sh) - 1)) * 32, r0 = (id >> sh) * 32;
  int tx = threadIdx.x, ty = threadIdx.y;  // (32, 8)
#pragma unroll
  for (int i = 0; i < 4; i++)
    tile[ty + i * 8][tx] = in[(long)(r0 + ty + i * 8) * C + c0 + tx];
  __syncthreads();
#pragma unroll
  for (int i = 0; i < 4; i++) {
    int oc = ty + i * 8;
    out[(long)(c0 + oc) * 2048 + r0 + tx] = f2bf(tile[tx][oc]);
  }
}

// ------ transpose v slice of qkv (bf16): vT[b][kh][h][l] = qkv[b*L+l][3072+kh*128+h] ------
__global__ __launch_bounds__(256) void transpose_v(const unsigned short* __restrict__ qkv,
                                                   unsigned short* __restrict__ vT) {
  __shared__ unsigned short tile[32][33];
  int l0 = blockIdx.x * 32, h0 = blockIdx.y * 32;
  int bk = blockIdx.z;  // b*8 + kh
  int b = bk >> 3, kh = bk & 7;
  int tx = threadIdx.x, ty = threadIdx.y;  // (32, 8)
  const unsigned short* src = qkv + (long)b * L_ * 4096 + 3072 + kh * 128;
#pragma unroll
  for (int i = 0; i < 4; i++)
    tile[ty + i * 8][tx] = src[(long)(l0 + ty + i * 8) * 4096 + h0 + tx];
  __syncthreads();
  unsigned short* dst = vT + (long)bk * HD_ * L_;
#pragma unroll
  for (int i = 0; i < 4; i++)
    dst[(long)(h0 + ty + i * 8) * L_ + l0 + tx] = tile[tx][ty + i * 8];
}

// ---------------- 128x128-tile bf16 MFMA GEMM:  C = A(MxK) * Bt(NxK)^T ----------------
template <int OUT_BF16>
__global__ __launch_bounds__(256, 2) void gemm128(const unsigned short* __restrict__ A,
                                                  const unsigned short* __restrict__ Bt,
                                                  void* __restrict__ C,
                                                  int M, int N, int K) {
  __shared__ unsigned short As[128 * 64];
  __shared__ unsigned short Bs[128 * 64];
  const int t = threadIdx.x;
  const int lane = t & 63, w = t >> 6;
  const int wy = w >> 1, wx = w & 1;
  const int col = lane & 15, quad = lane >> 4;
  const long m0 = (long)blockIdx.y * 128, n0 = (long)blockIdx.x * 128;
  floatx4 acc[4][4];
#pragma unroll
  for (int i = 0; i < 4; i++)
#pragma unroll
    for (int j = 0; j < 4; j++) acc[i][j] = (floatx4)0.0f;
  const int rs = t >> 3, bs = t & 7;  // staging row / 16B-block
  for (int kt = 0; kt < K; kt += 64) {
#pragma unroll
    for (int i = 0; i < 4; i++) {
      int r = i * 32 + rs;
      gl_lds16(A + (m0 + r) * (long)K + kt + ((bs ^ (r & 7)) << 3),
               &As[(i * 32 + w * 8) * 64]);
      gl_lds16(Bt + (n0 + r) * (long)K + kt + ((bs ^ (r & 7)) << 3),
               &Bs[(i * 32 + w * 8) * 64]);
    }
    __syncthreads();
#pragma unroll
    for (int ks = 0; ks < 2; ks++) {
      short8 af[4], bf[4];
#pragma unroll
      for (int mi = 0; mi < 4; mi++) {
        int row = wy * 64 + mi * 16 + col;
        int blk = ks * 4 + quad;
        af[mi] = *(const short8*)&As[row * 64 + ((blk ^ (row & 7)) << 3)];
      }
#pragma unroll
      for (int ni = 0; ni < 4; ni++) {
        int row = wx * 64 + ni * 16 + col;
        int blk = ks * 4 + quad;
        bf[ni] = *(const short8*)&Bs[row * 64 + ((blk ^ (row & 7)) << 3)];
      }
#pragma unroll
      for (int mi = 0; mi < 4; mi++)
#pragma unroll
        for (int ni = 0; ni < 4; ni++)
          acc[mi][ni] = __builtin_amdgcn_mfma_f32_16x16x32_bf16(af[mi], bf[ni],
                                                                acc[mi][ni], 0, 0, 0);
    }
    __syncthreads();
  }
#pragma unroll
  for (int mi = 0; mi < 4; mi++)
#pragma unroll
    for (int r = 0; r < 4; r++) {
      long row = m0 + wy * 64 + mi * 16 + quad * 4 + r;
#pragma unroll
      for (int ni = 0; ni < 4; ni++) {
        long cg = n0 + wx * 64 + ni * 16 + col;
        float val = acc[mi][ni][r];
        if (OUT_BF16)
          ((unsigned short*)C)[row * N + cg] = f2bf(val);
        else
          ((float*)C)[row * N + cg] = val;
      }
    }
}

// ------------- RMS-norm + RoPE + scale + relayout: one wave per (row, head) -------------
__global__ __launch_bounds__(256) void rmsrope(const unsigned short* __restrict__ qkv,
                                               const int* __restrict__ pos,
                                               const float* __restrict__ qw,
                                               const float* __restrict__ kw,
                                               unsigned short* __restrict__ qo,
                                               unsigned short* __restrict__ ko) {
  const int t = threadIdx.x, lane = t & 63, w = t >> 6;
  const int gid = blockIdx.x * 4 + w;  // 0 .. 4096*24-1
  const int row = gid / 24;
  const int hd = gid - row * 24;  // 0..15 q, 16..23 k
  const int b = row >> 11, l = row & 2047;
  const unsigned short* src = qkv + (long)row * 4096 + hd * 128;
  float x0 = bf2f(src[lane]);
  float x1 = bf2f(src[lane + 64]);
  float ss = x0 * x0 + x1 * x1;
#pragma unroll
  for (int off = 32; off; off >>= 1) ss += __shfl_xor(ss, off);
  float inv = 1.0f / sqrtf(ss * (1.0f / 128.0f) + 1e-6f);
  const float* nw = (hd < 16) ? qw : kw;
  x0 = nw[lane] * x0 * inv;
  x1 = nw[lane + 64] * x1 * inv;
  float p = (float)pos[row];
  // timescale = 1e6^(lane/64) -> 1/ts = exp2(-lane * log2(1e6)/64)
  float ang = p * exp2f((float)lane * -0.31143075889f);
  float s, c;
  sincosf(ang, &s, &c);
  float o0 = x0 * c - x1 * s;
  float o1 = x1 * c + x0 * s;
  unsigned short* dst;
  if (hd < 16) {
    const float QSC = 0.08838834764831845f * 1.4426950408889634f;  // H^-0.5 * log2e
    o0 *= QSC;
    o1 *= QSC;
    dst = qo + (((long)b * NH_ + hd) * L_ + l) * HD_;
  } else {
    dst = ko + (((long)b * KH_ + (hd - 16)) * L_ + l) * HD_;
  }
  dst[lane] = f2bf(o0);
  dst[lane + 64] = f2bf(o1);
}

// ------- flash attention: Q-tile 128 (4 waves x 32 rows), KV-tile 64, contiguous KV -------
// Fixed-max softmax: after rms-norm ||q||=||k||=sqrt(H) exactly (RoPE is a rotation),
// so |q.k| * H^-0.5 * log2e <= 16.33 < 17 -> p = exp2(s - 17), no running max/rescale.
// LDS 32 KB: P aliases the K tile (K fully consumed once S computed) -> 4+ blocks/CU.
// Heavy-first dispatch (qt = 15 - bx) for LPT-style makespan packing.
// KV walk is contiguous from s=0 for every block: keeps K/V L2-resident (R4 lesson).
__global__ __launch_bounds__(256, 4) void flash(const unsigned short* __restrict__ Q,
                                                const unsigned short* __restrict__ Kg,
                                                const unsigned short* __restrict__ VT,
                                                unsigned short* __restrict__ Og) {
  __shared__ unsigned short Ks[64 * 128];  // K tile; aliased as P (128x64) mid-step
  __shared__ unsigned short Vs[128 * 64];  // V^T tile (h-major), xor-swizzled
  unsigned short* Ps = Ks;
  const int n = blockIdx.y, b = blockIdx.z;
  const int qt = 15 - blockIdx.x;  // heavy blocks dispatch first
  const int t = threadIdx.x, lane = t & 63, w = t >> 6;
  const int col = lane & 15, quad = lane >> 4;
  const int kvh = n >> 1;
  const unsigned short* kb = Kg + ((long)b * KH_ + kvh) * L_ * HD_;
  const unsigned short* vtb = VT + ((long)b * KH_ + kvh) * HD_ * L_;  // [h][l]
  const int l0 = qt * 128;
  const int steps = 2 * qt + 2;
  const unsigned short* qb = Q + (((long)b * NH_ + n) * L_ + l0) * HD_;

  // wave w owns Q rows [32w, 32w+32): 2 m-frags
  short8 qf[2][4];
#pragma unroll
  for (int mi = 0; mi < 2; mi++)
#pragma unroll
    for (int ks = 0; ks < 4; ks++)
      qf[mi][ks] = *(const short8*)(qb + (w * 32 + mi * 16 + col) * 128 + ks * 32 + quad * 8);

  floatx4 o[2][8];
#pragma unroll
  for (int mi = 0; mi < 2; mi++)
#pragma unroll
    for (int nf = 0; nf < 8; nf++) o[mi][nf] = (floatx4)0.0f;
  float lrow[2][4];
#pragma unroll
  for (int mi = 0; mi < 2; mi++)
#pragma unroll
    for (int r = 0; r < 4; r++) lrow[mi][r] = 0.0f;

  for (int st = 0; st < steps; st++) {
    const int s0 = st * 64;
    // stage K tile (64 x 128): 4 x gl_lds16 per thread
    {
      const int rK = t >> 4, blkK = t & 15;
#pragma unroll
      for (int i = 0; i < 4; i++) {
        int r = i * 16 + rK;
        int gblk = (blkK & 8) | ((blkK ^ r) & 7);
        gl_lds16(kb + (long)(s0 + r) * 128 + gblk * 8, &Ks[(i * 16 + w * 4) * 128]);
      }
    }
    // stage V^T tile (128 x 64): 4 x gl_lds16 per thread
    {
      const int rV = t >> 3, blkV = t & 7;
#pragma unroll
      for (int j = 0; j < 4; j++) {
        int r = j * 32 + rV;
        int gblk = (blkV ^ r) & 7;
        gl_lds16(vtb + (long)r * L_ + s0 + gblk * 8, &Vs[(j * 32 + w * 8) * 64]);
      }
    }
    __syncthreads();

    // S = Q K^T  (32 rows per wave x 64 cols)
    floatx4 sa[2][4];
#pragma unroll
    for (int mi = 0; mi < 2; mi++)
#pragma unroll
      for (int sf = 0; sf < 4; sf++) sa[mi][sf] = (floatx4)0.0f;
#pragma unroll
    for (int ks = 0; ks < 4; ks++) {
      short8 bf[4];
#pragma unroll
      for (int sf = 0; sf < 4; sf++) {
        int srow = sf * 16 + col;
        int blk = ks * 4 + quad;
        bf[sf] = *(const short8*)&Ks[srow * 128 + (((blk & 8) | ((blk ^ srow) & 7)) << 3)];
      }
#pragma unroll
      for (int mi = 0; mi < 2; mi++)
#pragma unroll
        for (int sf = 0; sf < 4; sf++)
          sa[mi][sf] = __builtin_amdgcn_mfma_f32_16x16x32_bf16(qf[mi][ks], bf[sf],
                                                               sa[mi][sf], 0, 0, 0);
    }
    __syncthreads();  // all waves done reading Ks before P overwrites it

    // causal mask: only the last two steps touch the diagonal
    if (st >= steps - 2) {
#pragma unroll
      for (int mi = 0; mi < 2; mi++)
#pragma unroll
        for (int sf = 0; sf < 4; sf++)
#pragma unroll
          for (int r = 0; r < 4; r++) {
            int lr = l0 + w * 32 + mi * 16 + quad * 4 + r;
            int sr = s0 + sf * 16 + col;
            if (sr > lr) sa[mi][sf][r] = -3.0e38f;
          }
    }

    // fixed-max softmax + P -> LDS (A-operand layout, stride-64, xor-swizzled)
#pragma unroll
    for (int mi = 0; mi < 2; mi++)
#pragma unroll
      for (int sf = 0; sf < 4; sf++)
#pragma unroll
        for (int r = 0; r < 4; r++) {
          float pv = exp2f(sa[mi][sf][r] - 17.0f);
          lrow[mi][r] += pv;
          int prow = w * 32 + mi * 16 + quad * 4 + r;
          int scol = sf * 16 + col;
          Ps[prow * 64 + (((scol >> 3) ^ (prow & 7)) << 3) + (scol & 7)] = f2bf(pv);
        }

    // O += P V  (own P rows only -> no barrier between P write and read)
#pragma unroll
    for (int ks = 0; ks < 2; ks++) {
      short8 pf[2];
#pragma unroll
      for (int mi = 0; mi < 2; mi++) {
        int prow = w * 32 + mi * 16 + col;
        int blk = ks * 4 + quad;
        pf[mi] = *(const short8*)&Ps[prow * 64 + ((blk ^ (prow & 7)) << 3)];
      }
      short8 vf[8];
#pragma unroll
      for (int nf = 0; nf < 8; nf++) {
        int h = nf * 16 + col;
        int blk = ks * 4 + quad;
        vf[nf] = *(const short8*)&Vs[h * 64 + ((blk ^ (h & 7)) << 3)];
      }
#pragma unroll
      for (int mi = 0; mi < 2; mi++)
#pragma unroll
        for (int nf = 0; nf < 8; nf++)
          o[mi][nf] = __builtin_amdgcn_mfma_f32_16x16x32_bf16(pf[mi], vf[nf],
                                                              o[mi][nf], 0, 0, 0);
    }
    __syncthreads();  // P/V consumed before next staging
  }

  // epilogue: reduce lrow across the 16 col-lanes, O /= l, write (B, L, N, H)
#pragma unroll
  for (int mi = 0; mi < 2; mi++)
#pragma unroll
    for (int r = 0; r < 4; r++) {
      float s = lrow[mi][r];
#pragma unroll
      for (int off = 8; off; off >>= 1) s += __shfl_xor(s, off);
      float inv = 1.0f / s;
      int lg = l0 + w * 32 + mi * 16 + quad * 4 + r;
      unsigned short* dst = Og + (((long)b * L_ + lg) * NH_ + n) * HD_;
#pragma unroll
      for (int nf = 0; nf < 8; nf++)
        dst[nf * 16 + col] = f2bf(o[mi][nf][r] * inv);
    }
}

// ---------------- launcher ----------------
extern "C" void kernel_launch(void* const* d_in, const int* in_sizes, int n_in,
                              void* d_out, int out_size, void* d_ws, size_t ws_size,
                              hipStream_t stream) {
  const float* x = (const float*)d_in[0];
  const int* pos = (const int*)d_in[1];
  // d_in[2] = attn_mask (causal tril) -- implicit in the flash kernel
  const float* wq = (const float*)d_in[3];
  const float* wk = (const float*)d_in[4];
  const float* wv = (const float*)d_in[5];
  const float* wo = (const float*)d_in[6];
  const float* qnw = (const float*)d_in[7];
  const float* knw = (const float*)d_in[8];
  float* out = (float*)d_out;

  // workspace layout (bytes)
  char* ws = (char*)d_ws;
  unsigned short* xb     = (unsigned short*)(ws + 0);          // 16 MiB  (4096 x 2048 bf16)
  unsigned short* wqkv_t = (unsigned short*)(ws + 16777216);   // 16 MiB  (4096 x 2048 bf16)
  unsigned short* wo_t   = (unsigned short*)(ws + 33554432);   //  8 MiB  (2048 x 2048 bf16)
  unsigned short* qkv    = (unsigned short*)(ws + 41943040);   // 32 MiB  (4096 x 4096 bf16)
  unsigned short* q      = (unsigned short*)(ws + 75497472);   // 16 MiB  (B,N,L,H)
  unsigned short* k      = (unsigned short*)(ws + 92274688);   //  8 MiB  (B,K,L,H)
  unsigned short* vT     = (unsigned short*)(ws + 100663296);  //  8 MiB  (B,K,H,L)
  unsigned short* ao     = (unsigned short*)(ws + 109051904);  // 16 MiB  (B,L,N,H)
  if (ws_size < 125829120) return;  // insufficient workspace -> fail loudly

  cvt_f32_bf16<<<8192, 256, 0, stream>>>(x, xb);
  dim3 tb(32, 8);
  transpose_all<<<12288, tb, 0, stream>>>(wq, wk, wv, wo, wqkv_t, wo_t);
  gemm128<1><<<dim3(32, 32), 256, 0, stream>>>(xb, wqkv_t, qkv, 4096, 4096, 2048);
  rmsrope<<<24576, 256, 0, stream>>>(qkv, pos, qnw, knw, q, k);
  transpose_v<<<dim3(64, 4, 16), tb, 0, stream>>>(qkv, vT);
  flash<<<dim3(16, NH_, B_), 256, 0, stream>>>(q, k, vT, ao);
  gemm128<0><<<dim3(16, 32), 256, 0, stream>>>(ao, wo_t, out, 4096, 2048, 2048);
}

// Round 6
// 374.751 us; speedup vs baseline: 2.0324x; 2.0324x over previous
//
#include <hip/hip_runtime.h>

// Problem constants
#define B_ 2
#define L_ 2048
#define D_ 2048
#define NH_ 16
#define KH_ 8
#define HD_ 128

typedef __attribute__((ext_vector_type(8))) short short8;
typedef __attribute__((ext_vector_type(4))) float floatx4;

__device__ __forceinline__ unsigned short f2bf(float f) {
  unsigned u = __float_as_uint(f);
  unsigned r = (u + 0x7fffu + ((u >> 16) & 1u)) >> 16;
  return (unsigned short)r;
}
__device__ __forceinline__ float bf2f(unsigned short h) {
  return __uint_as_float(((unsigned)h) << 16);
}
__device__ __forceinline__ void gl_lds16(const void* g, void* l) {
  __builtin_amdgcn_global_load_lds(
      (const __attribute__((address_space(1))) unsigned int*)g,
      (__attribute__((address_space(3))) unsigned int*)l, 16, 0, 0);
}

// ---------------- convert x: fp32 -> bf16 ----------------
__global__ __launch_bounds__(256) void cvt_f32_bf16(const float* __restrict__ in,
                                                    unsigned short* __restrict__ out) {
  long i = ((long)blockIdx.x * 256 + threadIdx.x) * 4;
  float4 v = *(const float4*)(in + i);
  ushort4 o;
  o.x = f2bf(v.x); o.y = f2bf(v.y); o.z = f2bf(v.z); o.w = f2bf(v.w);
  *(ushort4*)(out + i) = o;
}

// ----- fused transpose+convert of all weights: one launch, task decoded from blockIdx -----
__global__ __launch_bounds__(256) void transpose_all(const float* __restrict__ wq,
                                                     const float* __restrict__ wk,
                                                     const float* __restrict__ wv,
                                                     const float* __restrict__ wo,
                                                     unsigned short* __restrict__ wqkv_t,
                                                     unsigned short* __restrict__ wo_t) {
  __shared__ float tile[32][33];
  int id = blockIdx.x;
  const float* in;
  unsigned short* out;
  int C, sh;
  if (id < 4096) {
    in = wq; out = wqkv_t; C = 2048; sh = 6;
  } else if (id < 6144) {
    in = wk; out = wqkv_t + 2048L * 2048; C = 1024; sh = 5; id -= 4096;
  } else if (id < 8192) {
    in = wv; out = wqkv_t + 3072L * 2048; C = 1024; sh = 5; id -= 6144;
  } else {
    in = wo; out = wo_t; C = 2048; sh = 6; id -= 8192;
  }
  int c0 = (id & ((1 << sh) - 1)) * 32, r0 = (id >> sh) * 32;
  int tx = threadIdx.x, ty = threadIdx.y;  // (32, 8)
#pragma unroll
  for (int i = 0; i < 4; i++)
    tile[ty + i * 8][tx] = in[(long)(r0 + ty + i * 8) * C + c0 + tx];
  __syncthreads();
#pragma unroll
  for (int i = 0; i < 4; i++) {
    int oc = ty + i * 8;
    out[(long)(c0 + oc) * 2048 + r0 + tx] = f2bf(tile[tx][oc]);
  }
}

// ------ transpose v slice of qkv (bf16): vT[b][kh][h][l] = qkv[b*L+l][3072+kh*128+h] ------
__global__ __launch_bounds__(256) void transpose_v(const unsigned short* __restrict__ qkv,
                                                   unsigned short* __restrict__ vT) {
  __shared__ unsigned short tile[32][33];
  int l0 = blockIdx.x * 32, h0 = blockIdx.y * 32;
  int bk = blockIdx.z;  // b*8 + kh
  int b = bk >> 3, kh = bk & 7;
  int tx = threadIdx.x, ty = threadIdx.y;  // (32, 8)
  const unsigned short* src = qkv + (long)b * L_ * 4096 + 3072 + kh * 128;
#pragma unroll
  for (int i = 0; i < 4; i++)
    tile[ty + i * 8][tx] = src[(long)(l0 + ty + i * 8) * 4096 + h0 + tx];
  __syncthreads();
  unsigned short* dst = vT + (long)bk * HD_ * L_;
#pragma unroll
  for (int i = 0; i < 4; i++)
    dst[(long)(h0 + ty + i * 8) * L_ + l0 + tx] = tile[tx][ty + i * 8];
}

// ---------------- 128x128-tile bf16 MFMA GEMM:  C = A(MxK) * Bt(NxK)^T ----------------
// launch_bounds(256,3): 3 blocks/CU -> unified reg cap ~170 (64 AGPR acc + ~106 VGPR).
// R3 measured 108 VGPR at (256,2); the cap shaves ~2 regs, not loop spills. Watch
// FETCH/WRITE next profile for spill evidence.
template <int OUT_BF16>
__global__ __launch_bounds__(256, 3) void gemm128(const unsigned short* __restrict__ A,
                                                  const unsigned short* __restrict__ Bt,
                                                  void* __restrict__ C,
                                                  int M, int N, int K) {
  __shared__ unsigned short As[128 * 64];
  __shared__ unsigned short Bs[128 * 64];
  const int t = threadIdx.x;
  const int lane = t & 63, w = t >> 6;
  const int wy = w >> 1, wx = w & 1;
  const int col = lane & 15, quad = lane >> 4;
  const long m0 = (long)blockIdx.y * 128, n0 = (long)blockIdx.x * 128;
  floatx4 acc[4][4];
#pragma unroll
  for (int i = 0; i < 4; i++)
#pragma unroll
    for (int j = 0; j < 4; j++) acc[i][j] = (floatx4)0.0f;
  const int rs = t >> 3, bs = t & 7;  // staging row / 16B-block
  for (int kt = 0; kt < K; kt += 64) {
#pragma unroll
    for (int i = 0; i < 4; i++) {
      int r = i * 32 + rs;
      gl_lds16(A + (m0 + r) * (long)K + kt + ((bs ^ (r & 7)) << 3),
               &As[(i * 32 + w * 8) * 64]);
      gl_lds16(Bt + (n0 + r) * (long)K + kt + ((bs ^ (r & 7)) << 3),
               &Bs[(i * 32 + w * 8) * 64]);
    }
    __syncthreads();
#pragma unroll
    for (int ks = 0; ks < 2; ks++) {
      short8 af[4], bf[4];
#pragma unroll
      for (int mi = 0; mi < 4; mi++) {
        int row = wy * 64 + mi * 16 + col;
        int blk = ks * 4 + quad;
        af[mi] = *(const short8*)&As[row * 64 + ((blk ^ (row & 7)) << 3)];
      }
#pragma unroll
      for (int ni = 0; ni < 4; ni++) {
        int row = wx * 64 + ni * 16 + col;
        int blk = ks * 4 + quad;
        bf[ni] = *(const short8*)&Bs[row * 64 + ((blk ^ (row & 7)) << 3)];
      }
#pragma unroll
      for (int mi = 0; mi < 4; mi++)
#pragma unroll
        for (int ni = 0; ni < 4; ni++)
          acc[mi][ni] = __builtin_amdgcn_mfma_f32_16x16x32_bf16(af[mi], bf[ni],
                                                                acc[mi][ni], 0, 0, 0);
    }
    __syncthreads();
  }
#pragma unroll
  for (int mi = 0; mi < 4; mi++)
#pragma unroll
    for (int r = 0; r < 4; r++) {
      long row = m0 + wy * 64 + mi * 16 + quad * 4 + r;
#pragma unroll
      for (int ni = 0; ni < 4; ni++) {
        long cg = n0 + wx * 64 + ni * 16 + col;
        float val = acc[mi][ni][r];
        if (OUT_BF16)
          ((unsigned short*)C)[row * N + cg] = f2bf(val);
        else
          ((float*)C)[row * N + cg] = val;
      }
    }
}

// ------------- RMS-norm + RoPE + scale + relayout: one wave per (row, head) -------------
__global__ __launch_bounds__(256) void rmsrope(const unsigned short* __restrict__ qkv,
                                               const int* __restrict__ pos,
                                               const float* __restrict__ qw,
                                               const float* __restrict__ kw,
                                               unsigned short* __restrict__ qo,
                                               unsigned short* __restrict__ ko) {
  const int t = threadIdx.x, lane = t & 63, w = t >> 6;
  const int gid = blockIdx.x * 4 + w;  // 0 .. 4096*24-1
  const int row = gid / 24;
  const int hd = gid - row * 24;  // 0..15 q, 16..23 k
  const int b = row >> 11, l = row & 2047;
  const unsigned short* src = qkv + (long)row * 4096 + hd * 128;
  float x0 = bf2f(src[lane]);
  float x1 = bf2f(src[lane + 64]);
  float ss = x0 * x0 + x1 * x1;
#pragma unroll
  for (int off = 32; off; off >>= 1) ss += __shfl_xor(ss, off);
  float inv = 1.0f / sqrtf(ss * (1.0f / 128.0f) + 1e-6f);
  const float* nw = (hd < 16) ? qw : kw;
  x0 = nw[lane] * x0 * inv;
  x1 = nw[lane + 64] * x1 * inv;
  float p = (float)pos[row];
  // timescale = 1e6^(lane/64) -> 1/ts = exp2(-lane * log2(1e6)/64)
  float ang = p * exp2f((float)lane * -0.31143075889f);
  float s, c;
  sincosf(ang, &s, &c);
  float o0 = x0 * c - x1 * s;
  float o1 = x1 * c + x0 * s;
  unsigned short* dst;
  if (hd < 16) {
    const float QSC = 0.08838834764831845f * 1.4426950408889634f;  // H^-0.5 * log2e
    o0 *= QSC;
    o1 *= QSC;
    dst = qo + (((long)b * NH_ + hd) * L_ + l) * HD_;
  } else {
    dst = ko + (((long)b * KH_ + (hd - 16)) * L_ + l) * HD_;
  }
  dst[lane] = f2bf(o0);
  dst[lane + 64] = f2bf(o1);
}

// ------- flash attention: Q-tile 128 (4 waves x 32 rows), KV-tile 64 -------
// R3 configuration restored exactly: launch_bounds(256,2) -- flash needs ~190 unified
// regs (64 AGPR o-acc + ~110 VGPR); capping tighter spills accumulators to scratch
// (R4/R5 regression: VGPR_Count 64, WRITE_SIZE 228-526 MB).
// Fixed-max softmax: after rms-norm ||q||=||k||=sqrt(H) exactly (RoPE is a rotation),
// so |q.k| * H^-0.5 * log2e <= 16.33 < 17 -> p = exp2(s - 17), no running max/rescale.
// KV walk contiguous from s=0 for every block keeps K/V L2-resident.
__global__ __launch_bounds__(256, 2) void flash(const unsigned short* __restrict__ Q,
                                                const unsigned short* __restrict__ Kg,
                                                const unsigned short* __restrict__ VT,
                                                unsigned short* __restrict__ Og) {
  __shared__ unsigned short Ks[64 * 128];  // K tile, xor-swizzled 16B blocks
  __shared__ unsigned short Vs[128 * 64];  // V^T tile (h-major), xor-swizzled
  __shared__ unsigned short Ps[128 * 72];  // P, row l, stride 72
  const int n = blockIdx.y, b = blockIdx.z;
  const int qt = b ? (15 - blockIdx.x) : blockIdx.x;
  const int t = threadIdx.x, lane = t & 63, w = t >> 6;
  const int col = lane & 15, quad = lane >> 4;
  const int kvh = n >> 1;
  const unsigned short* kb = Kg + ((long)b * KH_ + kvh) * L_ * HD_;
  const unsigned short* vtb = VT + ((long)b * KH_ + kvh) * HD_ * L_;  // [h][l]
  const int l0 = qt * 128;
  const int steps = 2 * qt + 2;
  const unsigned short* qb = Q + (((long)b * NH_ + n) * L_ + l0) * HD_;

  // wave w owns Q rows [32w, 32w+32): 2 m-frags
  short8 qf[2][4];
#pragma unroll
  for (int mi = 0; mi < 2; mi++)
#pragma unroll
    for (int ks = 0; ks < 4; ks++)
      qf[mi][ks] = *(const short8*)(qb + (w * 32 + mi * 16 + col) * 128 + ks * 32 + quad * 8);

  floatx4 o[2][8];
#pragma unroll
  for (int mi = 0; mi < 2; mi++)
#pragma unroll
    for (int nf = 0; nf < 8; nf++) o[mi][nf] = (floatx4)0.0f;
  float lrow[2][4];
#pragma unroll
  for (int mi = 0; mi < 2; mi++)
#pragma unroll
    for (int r = 0; r < 4; r++) lrow[mi][r] = 0.0f;

  for (int st = 0; st < steps; st++) {
    const int s0 = st * 64;
    // stage K tile (64 x 128): 4 x gl_lds16 per thread
    {
      const int rK = t >> 4, blkK = t & 15;
#pragma unroll
      for (int i = 0; i < 4; i++) {
        int r = i * 16 + rK;
        int gblk = (blkK & 8) | ((blkK ^ r) & 7);
        gl_lds16(kb + (long)(s0 + r) * 128 + gblk * 8, &Ks[(i * 16 + w * 4) * 128]);
      }
    }
    // stage V^T tile (128 x 64): 4 x gl_lds16 per thread
    {
      const int rV = t >> 3, blkV = t & 7;
#pragma unroll
      for (int j = 0; j < 4; j++) {
        int r = j * 32 + rV;
        int gblk = (blkV ^ r) & 7;
        gl_lds16(vtb + (long)r * L_ + s0 + gblk * 8, &Vs[(j * 32 + w * 8) * 64]);
      }
    }
    __syncthreads();

    // S = Q K^T  (32 rows per wave x 64 cols)
    floatx4 sa[2][4];
#pragma unroll
    for (int mi = 0; mi < 2; mi++)
#pragma unroll
      for (int sf = 0; sf < 4; sf++) sa[mi][sf] = (floatx4)0.0f;
#pragma unroll
    for (int ks = 0; ks < 4; ks++) {
      short8 bf[4];
#pragma unroll
      for (int sf = 0; sf < 4; sf++) {
        int srow = sf * 16 + col;
        int blk = ks * 4 + quad;
        bf[sf] = *(const short8*)&Ks[srow * 128 + (((blk & 8) | ((blk ^ srow) & 7)) << 3)];
      }
#pragma unroll
      for (int mi = 0; mi < 2; mi++)
#pragma unroll
        for (int sf = 0; sf < 4; sf++)
          sa[mi][sf] = __builtin_amdgcn_mfma_f32_16x16x32_bf16(qf[mi][ks], bf[sf],
                                                               sa[mi][sf], 0, 0, 0);
    }

    // causal mask: only the last two steps touch the diagonal
    if (st >= steps - 2) {
#pragma unroll
      for (int mi = 0; mi < 2; mi++)
#pragma unroll
        for (int sf = 0; sf < 4; sf++)
#pragma unroll
          for (int r = 0; r < 4; r++) {
            int lr = l0 + w * 32 + mi * 16 + quad * 4 + r;
            int sr = s0 + sf * 16 + col;
            if (sr > lr) sa[mi][sf][r] = -3.0e38f;
          }
    }

    // fixed-max softmax: p = exp2(s - 17); per-lane partial row sums only
#pragma unroll
    for (int mi = 0; mi < 2; mi++)
#pragma unroll
      for (int sf = 0; sf < 4; sf++)
#pragma unroll
        for (int r = 0; r < 4; r++) {
          float pv = exp2f(sa[mi][sf][r] - 17.0f);
          sa[mi][sf][r] = pv;
          lrow[mi][r] += pv;
        }

    // P -> LDS (A-operand layout); own rows only, no barrier needed
#pragma unroll
    for (int mi = 0; mi < 2; mi++)
#pragma unroll
      for (int sf = 0; sf < 4; sf++)
#pragma unroll
        for (int r = 0; r < 4; r++)
          Ps[(w * 32 + mi * 16 + quad * 4 + r) * 72 + sf * 16 + col] = f2bf(sa[mi][sf][r]);

    // O += P V
#pragma unroll
    for (int ks = 0; ks < 2; ks++) {
      short8 pf[2];
#pragma unroll
      for (int mi = 0; mi < 2; mi++)
        pf[mi] = *(const short8*)&Ps[(w * 32 + mi * 16 + col) * 72 + ks * 32 + quad * 8];
      short8 vf[8];
#pragma unroll
      for (int nf = 0; nf < 8; nf++) {
        int h = nf * 16 + col;
        int blk = ks * 4 + quad;
        vf[nf] = *(const short8*)&Vs[h * 64 + ((blk ^ (h & 7)) << 3)];
      }
#pragma unroll
      for (int mi = 0; mi < 2; mi++)
#pragma unroll
        for (int nf = 0; nf < 8; nf++)
          o[mi][nf] = __builtin_amdgcn_mfma_f32_16x16x32_bf16(pf[mi], vf[nf],
                                                              o[mi][nf], 0, 0, 0);
    }
    __syncthreads();
  }

  // epilogue: reduce lrow across the 16 col-lanes, O /= l, write (B, L, N, H)
#pragma unroll
  for (int mi = 0; mi < 2; mi++)
#pragma unroll
    for (int r = 0; r < 4; r++) {
      float s = lrow[mi][r];
#pragma unroll
      for (int off = 8; off; off >>= 1) s += __shfl_xor(s, off);
      float inv = 1.0f / s;
      int lg = l0 + w * 32 + mi * 16 + quad * 4 + r;
      unsigned short* dst = Og + (((long)b * L_ + lg) * NH_ + n) * HD_;
#pragma unroll
      for (int nf = 0; nf < 8; nf++)
        dst[nf * 16 + col] = f2bf(o[mi][nf][r] * inv);
    }
}

// ---------------- launcher ----------------
extern "C" void kernel_launch(void* const* d_in, const int* in_sizes, int n_in,
                              void* d_out, int out_size, void* d_ws, size_t ws_size,
                              hipStream_t stream) {
  const float* x = (const float*)d_in[0];
  const int* pos = (const int*)d_in[1];
  // d_in[2] = attn_mask (causal tril) -- implicit in the flash kernel
  const float* wq = (const float*)d_in[3];
  const float* wk = (const float*)d_in[4];
  const float* wv = (const float*)d_in[5];
  const float* wo = (const float*)d_in[6];
  const float* qnw = (const float*)d_in[7];
  const float* knw = (const float*)d_in[8];
  float* out = (float*)d_out;

  // workspace layout (bytes)
  char* ws = (char*)d_ws;
  unsigned short* xb     = (unsigned short*)(ws + 0);          // 16 MiB  (4096 x 2048 bf16)
  unsigned short* wqkv_t = (unsigned short*)(ws + 16777216);   // 16 MiB  (4096 x 2048 bf16)
  unsigned short* wo_t   = (unsigned short*)(ws + 33554432);   //  8 MiB  (2048 x 2048 bf16)
  unsigned short* qkv    = (unsigned short*)(ws + 41943040);   // 32 MiB  (4096 x 4096 bf16)
  unsigned short* q      = (unsigned short*)(ws + 75497472);   // 16 MiB  (B,N,L,H)
  unsigned short* k      = (unsigned short*)(ws + 92274688);   //  8 MiB  (B,K,L,H)
  unsigned short* vT     = (unsigned short*)(ws + 100663296);  //  8 MiB  (B,K,H,L)
  unsigned short* ao     = (unsigned short*)(ws + 109051904);  // 16 MiB  (B,L,N,H)
  if (ws_size < 125829120) return;  // insufficient workspace -> fail loudly

  cvt_f32_bf16<<<8192, 256, 0, stream>>>(x, xb);
  dim3 tb(32, 8);
  transpose_all<<<12288, tb, 0, stream>>>(wq, wk, wv, wo, wqkv_t, wo_t);
  gemm128<1><<<dim3(32, 32), 256, 0, stream>>>(xb, wqkv_t, qkv, 4096, 4096, 2048);
  rmsrope<<<24576, 256, 0, stream>>>(qkv, pos, qnw, knw, q, k);
  transpose_v<<<dim3(64, 4, 16), tb, 0, stream>>>(qkv, vT);
  flash<<<dim3(16, NH_, B_), 256, 0, stream>>>(q, k, vT, ao);
  gemm128<0><<<dim3(16, 32), 256, 0, stream>>>(ao, wo_t, out, 4096, 2048, 2048);
}

// Round 7
// 362.820 us; speedup vs baseline: 2.0992x; 1.0329x over previous
//
#include <hip/hip_runtime.h>

// Problem constants
#define B_ 2
#define L_ 2048
#define D_ 2048
#define NH_ 16
#define KH_ 8
#define HD_ 128

typedef __attribute__((ext_vector_type(8))) short short8;
typedef __attribute__((ext_vector_type(4))) short short4v;
typedef __attribute__((ext_vector_type(4))) float floatx4;

__device__ __forceinline__ unsigned short f2bf(float f) {
  unsigned u = __float_as_uint(f);
  unsigned r = (u + 0x7fffu + ((u >> 16) & 1u)) >> 16;
  return (unsigned short)r;
}
__device__ __forceinline__ float bf2f(unsigned short h) {
  return __uint_as_float(((unsigned)h) << 16);
}
__device__ __forceinline__ void gl_lds16(const void* g, void* l) {
  __builtin_amdgcn_global_load_lds(
      (const __attribute__((address_space(1))) unsigned int*)g,
      (__attribute__((address_space(3))) unsigned int*)l, 16, 0, 0);
}

// ---------------- convert x: fp32 -> bf16 ----------------
__global__ __launch_bounds__(256) void cvt_f32_bf16(const float* __restrict__ in,
                                                    unsigned short* __restrict__ out) {
  long i = ((long)blockIdx.x * 256 + threadIdx.x) * 4;
  float4 v = *(const float4*)(in + i);
  ushort4 o;
  o.x = f2bf(v.x); o.y = f2bf(v.y); o.z = f2bf(v.z); o.w = f2bf(v.w);
  *(ushort4*)(out + i) = o;
}

// ----- fused transpose+convert of all weights: one launch, task decoded from blockIdx -----
__global__ __launch_bounds__(256) void transpose_all(const float* __restrict__ wq,
                                                     const float* __restrict__ wk,
                                                     const float* __restrict__ wv,
                                                     const float* __restrict__ wo,
                                                     unsigned short* __restrict__ wqkv_t,
                                                     unsigned short* __restrict__ wo_t) {
  __shared__ float tile[32][33];
  int id = blockIdx.x;
  const float* in;
  unsigned short* out;
  int C, sh;
  if (id < 4096) {
    in = wq; out = wqkv_t; C = 2048; sh = 6;
  } else if (id < 6144) {
    in = wk; out = wqkv_t + 2048L * 2048; C = 1024; sh = 5; id -= 4096;
  } else if (id < 8192) {
    in = wv; out = wqkv_t + 3072L * 2048; C = 1024; sh = 5; id -= 6144;
  } else {
    in = wo; out = wo_t; C = 2048; sh = 6; id -= 8192;
  }
  int c0 = (id & ((1 << sh) - 1)) * 32, r0 = (id >> sh) * 32;
  int tx = threadIdx.x, ty = threadIdx.y;  // (32, 8)
#pragma unroll
  for (int i = 0; i < 4; i++)
    tile[ty + i * 8][tx] = in[(long)(r0 + ty + i * 8) * C + c0 + tx];
  __syncthreads();
#pragma unroll
  for (int i = 0; i < 4; i++) {
    int oc = ty + i * 8;
    out[(long)(c0 + oc) * 2048 + r0 + tx] = f2bf(tile[tx][oc]);
  }
}

// ------ transpose v slice of qkv (bf16): vT[b][kh][h][l] = qkv[b*L+l][3072+kh*128+h] ------
__global__ __launch_bounds__(256) void transpose_v(const unsigned short* __restrict__ qkv,
                                                   unsigned short* __restrict__ vT) {
  __shared__ unsigned short tile[32][33];
  int l0 = blockIdx.x * 32, h0 = blockIdx.y * 32;
  int bk = blockIdx.z;  // b*8 + kh
  int b = bk >> 3, kh = bk & 7;
  int tx = threadIdx.x, ty = threadIdx.y;  // (32, 8)
  const unsigned short* src = qkv + (long)b * L_ * 4096 + 3072 + kh * 128;
#pragma unroll
  for (int i = 0; i < 4; i++)
    tile[ty + i * 8][tx] = src[(long)(l0 + ty + i * 8) * 4096 + h0 + tx];
  __syncthreads();
  unsigned short* dst = vT + (long)bk * HD_ * L_;
#pragma unroll
  for (int i = 0; i < 4; i++)
    dst[(long)(h0 + ty + i * 8) * L_ + l0 + tx] = tile[tx][ty + i * 8];
}

// ---------------- 128x128-tile bf16 MFMA GEMM:  C = A(MxK) * Bt(NxK)^T ----------------
template <int OUT_BF16>
__global__ __launch_bounds__(256, 3) void gemm128(const unsigned short* __restrict__ A,
                                                  const unsigned short* __restrict__ Bt,
                                                  void* __restrict__ C,
                                                  int M, int N, int K) {
  __shared__ unsigned short As[128 * 64];
  __shared__ unsigned short Bs[128 * 64];
  const int t = threadIdx.x;
  const int lane = t & 63, w = t >> 6;
  const int wy = w >> 1, wx = w & 1;
  const int col = lane & 15, quad = lane >> 4;
  const long m0 = (long)blockIdx.y * 128, n0 = (long)blockIdx.x * 128;
  floatx4 acc[4][4];
#pragma unroll
  for (int i = 0; i < 4; i++)
#pragma unroll
    for (int j = 0; j < 4; j++) acc[i][j] = (floatx4)0.0f;
  const int rs = t >> 3, bs = t & 7;  // staging row / 16B-block
  for (int kt = 0; kt < K; kt += 64) {
#pragma unroll
    for (int i = 0; i < 4; i++) {
      int r = i * 32 + rs;
      gl_lds16(A + (m0 + r) * (long)K + kt + ((bs ^ (r & 7)) << 3),
               &As[(i * 32 + w * 8) * 64]);
      gl_lds16(Bt + (n0 + r) * (long)K + kt + ((bs ^ (r & 7)) << 3),
               &Bs[(i * 32 + w * 8) * 64]);
    }
    __syncthreads();
#pragma unroll
    for (int ks = 0; ks < 2; ks++) {
      short8 af[4], bf[4];
#pragma unroll
      for (int mi = 0; mi < 4; mi++) {
        int row = wy * 64 + mi * 16 + col;
        int blk = ks * 4 + quad;
        af[mi] = *(const short8*)&As[row * 64 + ((blk ^ (row & 7)) << 3)];
      }
#pragma unroll
      for (int ni = 0; ni < 4; ni++) {
        int row = wx * 64 + ni * 16 + col;
        int blk = ks * 4 + quad;
        bf[ni] = *(const short8*)&Bs[row * 64 + ((blk ^ (row & 7)) << 3)];
      }
#pragma unroll
      for (int mi = 0; mi < 4; mi++)
#pragma unroll
        for (int ni = 0; ni < 4; ni++)
          acc[mi][ni] = __builtin_amdgcn_mfma_f32_16x16x32_bf16(af[mi], bf[ni],
                                                                acc[mi][ni], 0, 0, 0);
    }
    __syncthreads();
  }
#pragma unroll
  for (int mi = 0; mi < 4; mi++)
#pragma unroll
    for (int r = 0; r < 4; r++) {
      long row = m0 + wy * 64 + mi * 16 + quad * 4 + r;
#pragma unroll
      for (int ni = 0; ni < 4; ni++) {
        long cg = n0 + wx * 64 + ni * 16 + col;
        float val = acc[mi][ni][r];
        if (OUT_BF16)
          ((unsigned short*)C)[row * N + cg] = f2bf(val);
        else
          ((float*)C)[row * N + cg] = val;
      }
    }
}

// ------------- RMS-norm + RoPE + scale + relayout: one wave per (row, head) -------------
__global__ __launch_bounds__(256) void rmsrope(const unsigned short* __restrict__ qkv,
                                               const int* __restrict__ pos,
                                               const float* __restrict__ qw,
                                               const float* __restrict__ kw,
                                               unsigned short* __restrict__ qo,
                                               unsigned short* __restrict__ ko) {
  const int t = threadIdx.x, lane = t & 63, w = t >> 6;
  const int gid = blockIdx.x * 4 + w;  // 0 .. 4096*24-1
  const int row = gid / 24;
  const int hd = gid - row * 24;  // 0..15 q, 16..23 k
  const int b = row >> 11, l = row & 2047;
  const unsigned short* src = qkv + (long)row * 4096 + hd * 128;
  float x0 = bf2f(src[lane]);
  float x1 = bf2f(src[lane + 64]);
  float ss = x0 * x0 + x1 * x1;
#pragma unroll
  for (int off = 32; off; off >>= 1) ss += __shfl_xor(ss, off);
  float inv = 1.0f / sqrtf(ss * (1.0f / 128.0f) + 1e-6f);
  const float* nw = (hd < 16) ? qw : kw;
  x0 = nw[lane] * x0 * inv;
  x1 = nw[lane + 64] * x1 * inv;
  float p = (float)pos[row];
  // timescale = 1e6^(lane/64) -> 1/ts = exp2(-lane * log2(1e6)/64)
  float ang = p * exp2f((float)lane * -0.31143075889f);
  float s, c;
  sincosf(ang, &s, &c);
  float o0 = x0 * c - x1 * s;
  float o1 = x1 * c + x0 * s;
  unsigned short* dst;
  if (hd < 16) {
    const float QSC = 0.08838834764831845f * 1.4426950408889634f;  // H^-0.5 * log2e
    o0 *= QSC;
    o1 *= QSC;
    dst = qo + (((long)b * NH_ + hd) * L_ + l) * HD_;
  } else {
    dst = ko + (((long)b * KH_ + (hd - 16)) * L_ + l) * HD_;
  }
  dst[lane] = f2bf(o0);
  dst[lane + 64] = f2bf(o1);
}

// ------- flash attention, transpose-free: S^T = K Q^T, O^T += V^T P^T -------
// S^T's C-layout (row = s = quad*4+r, col = l = lane&15) IS the B-operand layout of
// v_mfma_f32_16x16x16_bf16 (n = lane&15, k = quad*4+j), so P^T feeds PV directly from
// registers -- no P LDS round-trip (was 32 ds_write_b16 + 4 ds_read_b128 per wave-step).
// Fixed-max softmax: ||q||=||k||=sqrt(H) after rms-norm (RoPE is a rotation) ->
// |q.k|*H^-0.5*log2e <= 16.33 < 17 -> p = exp2(s-17), no running max / rescale.
// launch_bounds(256,2): flash needs ~170 unified regs; tighter caps spill to scratch
// (R4/R5: VGPR=64, WRITE 228-526 MB). KV walk contiguous from s=0 keeps K/V L2-resident.
__global__ __launch_bounds__(256, 2) void flash(const unsigned short* __restrict__ Q,
                                                const unsigned short* __restrict__ Kg,
                                                const unsigned short* __restrict__ VT,
                                                unsigned short* __restrict__ Og) {
  __shared__ unsigned short Ks[64 * 128];  // K tile, xor-swizzled 16B blocks
  __shared__ unsigned short Vs[128 * 64];  // V^T tile (h-major), xor-swizzled
  const int n = blockIdx.y, b = blockIdx.z;
  const int qt = b ? (15 - blockIdx.x) : blockIdx.x;
  const int t = threadIdx.x, lane = t & 63, w = t >> 6;
  const int col = lane & 15, quad = lane >> 4;
  const int kvh = n >> 1;
  const unsigned short* kb = Kg + ((long)b * KH_ + kvh) * L_ * HD_;
  const unsigned short* vtb = VT + ((long)b * KH_ + kvh) * HD_ * L_;  // [h][l]
  const int l0 = qt * 128;
  const int steps = 2 * qt + 2;
  const unsigned short* qb = Q + (((long)b * NH_ + n) * L_ + l0) * HD_;

  // wave w owns Q rows [32w, 32w+32): mi=0 -> rows [32w,32w+16), mi=1 -> +16
  short8 qf[2][4];
#pragma unroll
  for (int mi = 0; mi < 2; mi++)
#pragma unroll
    for (int ks = 0; ks < 4; ks++)
      qf[mi][ks] = *(const short8*)(qb + (w * 32 + mi * 16 + col) * 128 + ks * 32 + quad * 8);

  // O^T accumulators: D[m=h][n=l]; col = l = lane&15, row = h-part = quad*4+r
  floatx4 o[2][8];
#pragma unroll
  for (int mi = 0; mi < 2; mi++)
#pragma unroll
    for (int nf = 0; nf < 8; nf++) o[mi][nf] = (floatx4)0.0f;
  float lrow[2] = {0.0f, 0.0f};  // per-lane partial row-sum for l = l0+w*32+mi*16+col

  for (int st = 0; st < steps; st++) {
    const int s0 = st * 64;
    // stage K tile (64 x 128): 4 x gl_lds16 per thread
    {
      const int rK = t >> 4, blkK = t & 15;
#pragma unroll
      for (int i = 0; i < 4; i++) {
        int r = i * 16 + rK;
        int gblk = (blkK & 8) | ((blkK ^ r) & 7);
        gl_lds16(kb + (long)(s0 + r) * 128 + gblk * 8, &Ks[(i * 16 + w * 4) * 128]);
      }
    }
    // stage V^T tile (128 x 64): 4 x gl_lds16 per thread
    {
      const int rV = t >> 3, blkV = t & 7;
#pragma unroll
      for (int j = 0; j < 4; j++) {
        int r = j * 32 + rV;
        int gblk = (blkV ^ r) & 7;
        gl_lds16(vtb + (long)r * L_ + s0 + gblk * 8, &Vs[(j * 32 + w * 8) * 64]);
      }
    }
    __syncthreads();

    // S^T = K Q^T: A = K-frag (LDS), B = Q-frag (regs). Rows = s, cols = l.
    floatx4 sa[2][4];
#pragma unroll
    for (int mi = 0; mi < 2; mi++)
#pragma unroll
      for (int sf = 0; sf < 4; sf++) sa[mi][sf] = (floatx4)0.0f;
#pragma unroll
    for (int ks = 0; ks < 4; ks++) {
      short8 bf[4];
#pragma unroll
      for (int sf = 0; sf < 4; sf++) {
        int srow = sf * 16 + col;
        int blk = ks * 4 + quad;
        bf[sf] = *(const short8*)&Ks[srow * 128 + (((blk & 8) | ((blk ^ srow) & 7)) << 3)];
      }
#pragma unroll
      for (int mi = 0; mi < 2; mi++)
#pragma unroll
        for (int sf = 0; sf < 4; sf++)
          sa[mi][sf] = __builtin_amdgcn_mfma_f32_16x16x32_bf16(bf[sf], qf[mi][ks],
                                                               sa[mi][sf], 0, 0, 0);
    }

    // causal mask (S^T indices: s = s0+sf*16+quad*4+r, l = l0+w*32+mi*16+col)
    if (st >= steps - 2) {
#pragma unroll
      for (int mi = 0; mi < 2; mi++) {
        int lg = l0 + w * 32 + mi * 16 + col;
#pragma unroll
        for (int sf = 0; sf < 4; sf++)
#pragma unroll
          for (int r = 0; r < 4; r++) {
            int sg = s0 + sf * 16 + quad * 4 + r;
            if (sg > lg) sa[mi][sf][r] = -3.0e38f;
          }
      }
    }

    // fixed-max softmax + pack P^T B-frags in-register (no LDS round-trip)
    short4v pb[2][4];
#pragma unroll
    for (int mi = 0; mi < 2; mi++)
#pragma unroll
      for (int sf = 0; sf < 4; sf++) {
#pragma unroll
        for (int r = 0; r < 4; r++) {
          float pv = exp2f(sa[mi][sf][r] - 17.0f);
          lrow[mi] += pv;
          pb[mi][sf][r] = (short)f2bf(pv);
        }
      }

    // O^T += V^T P^T via 16x16x16 MFMA: A = V^T (m=h, k=s from LDS), B = P^T (regs)
#pragma unroll
    for (int ks = 0; ks < 4; ks++) {  // k = s range [16ks, 16ks+16)
#pragma unroll
      for (int nf = 0; nf < 8; nf++) {
        int h = nf * 16 + col;
        int soff = ks * 16 + quad * 4;  // 4 bf16 at this s offset
        int blk = soff >> 3;
        short4v va = *(const short4v*)&Vs[h * 64 + ((blk ^ (h & 7)) << 3) + (soff & 7)];
#pragma unroll
        for (int mi = 0; mi < 2; mi++)
          o[mi][nf] = __builtin_amdgcn_mfma_f32_16x16x16bf16_1k(va, pb[mi][ks],
                                                                o[mi][nf], 0, 0, 0);
      }
    }
    __syncthreads();
  }

  // epilogue: reduce lrow across quads (same l in lanes l, l+16, l+32, l+48),
  // O^T /= l, write O to (B, L, N, H) with ushort4 stores
#pragma unroll
  for (int mi = 0; mi < 2; mi++) {
    float s = lrow[mi];
    s += __shfl_xor(s, 16);
    s += __shfl_xor(s, 32);
    float inv = 1.0f / s;
    int lg = l0 + w * 32 + mi * 16 + col;
    unsigned short* dst = Og + (((long)b * L_ + lg) * NH_ + n) * HD_;
#pragma unroll
    for (int nf = 0; nf < 8; nf++) {
      ushort4 ov;
      ov.x = f2bf(o[mi][nf][0] * inv);
      ov.y = f2bf(o[mi][nf][1] * inv);
      ov.z = f2bf(o[mi][nf][2] * inv);
      ov.w = f2bf(o[mi][nf][3] * inv);
      *(ushort4*)(dst + nf * 16 + quad * 4) = ov;
    }
  }
}

// ---------------- launcher ----------------
extern "C" void kernel_launch(void* const* d_in, const int* in_sizes, int n_in,
                              void* d_out, int out_size, void* d_ws, size_t ws_size,
                              hipStream_t stream) {
  const float* x = (const float*)d_in[0];
  const int* pos = (const int*)d_in[1];
  // d_in[2] = attn_mask (causal tril) -- implicit in the flash kernel
  const float* wq = (const float*)d_in[3];
  const float* wk = (const float*)d_in[4];
  const float* wv = (const float*)d_in[5];
  const float* wo = (const float*)d_in[6];
  const float* qnw = (const float*)d_in[7];
  const float* knw = (const float*)d_in[8];
  float* out = (float*)d_out;

  // workspace layout (bytes)
  char* ws = (char*)d_ws;
  unsigned short* xb     = (unsigned short*)(ws + 0);          // 16 MiB  (4096 x 2048 bf16)
  unsigned short* wqkv_t = (unsigned short*)(ws + 16777216);   // 16 MiB  (4096 x 2048 bf16)
  unsigned short* wo_t   = (unsigned short*)(ws + 33554432);   //  8 MiB  (2048 x 2048 bf16)
  unsigned short* qkv    = (unsigned short*)(ws + 41943040);   // 32 MiB  (4096 x 4096 bf16)
  unsigned short* q      = (unsigned short*)(ws + 75497472);   // 16 MiB  (B,N,L,H)
  unsigned short* k      = (unsigned short*)(ws + 92274688);   //  8 MiB  (B,K,L,H)
  unsigned short* vT     = (unsigned short*)(ws + 100663296);  //  8 MiB  (B,K,H,L)
  unsigned short* ao     = (unsigned short*)(ws + 109051904);  // 16 MiB  (B,L,N,H)
  if (ws_size < 125829120) return;  // insufficient workspace -> fail loudly

  cvt_f32_bf16<<<8192, 256, 0, stream>>>(x, xb);
  dim3 tb(32, 8);
  transpose_all<<<12288, tb, 0, stream>>>(wq, wk, wv, wo, wqkv_t, wo_t);
  gemm128<1><<<dim3(32, 32), 256, 0, stream>>>(xb, wqkv_t, qkv, 4096, 4096, 2048);
  rmsrope<<<24576, 256, 0, stream>>>(qkv, pos, qnw, knw, q, k);
  transpose_v<<<dim3(64, 4, 16), tb, 0, stream>>>(qkv, vT);
  flash<<<dim3(16, NH_, B_), 256, 0, stream>>>(q, k, vT, ao);
  gemm128<0><<<dim3(16, 32), 256, 0, stream>>>(ao, wo_t, out, 4096, 2048, 2048);
}